// Round 13
// baseline (698.756 us; speedup 1.0000x reference)
//
#include <hip/hip_runtime.h>
#include <math.h>

#define HID 128
#define NRBF 50
#define NLAYERS 6
#define CUTV 5.0f
#define KNOTS 1024            // intervals
#define TSCALE 204.8f         // KNOTS / CUTV
#define TINV   0.0048828125f  // CUTV / KNOTS
#define TROWS  (KNOTS + 1)    // paired rows j=0..KNOTS
#define TRWORDS 512           // [h][4]: {dk, dv0, dv1, dv2} paired-bf16 words
#define TSTRIDE ((size_t)TROWS * TRWORDS)
#define WCOLS 1408            // 128 q | 512 kv-permuted | 384 vecW | 384 oW
#define KB 16                 // knot-pairs per table-build block
#define TBLK ((TROWS + KB - 1)/KB)          // 65
#define TB   (TBLK*NLAYERS)                 // 390
#define NEB  ((TROWS + 1)/2)                // 513
#define WTB  ((WCOLS/32)*NLAYERS)           // 264

typedef unsigned int  uint32;
typedef unsigned short ushort16;
typedef __attribute__((ext_vector_type(8))) short short8;
typedef __attribute__((ext_vector_type(4))) float f32x4;

__device__ __forceinline__ float siluf(float x){ return x / (1.0f + __expf(-x)); }
__device__ __forceinline__ float lerpf(float a, float b, float f){ return fmaf(f, b - a, a); }
__device__ __forceinline__ ushort16 f2b(float x){
    uint32 u = __float_as_uint(x);
    u += 0x7fffu + ((u >> 16) & 1u);
    return (ushort16)(u >> 16);
}
__device__ __forceinline__ float b2f(ushort16 u){ return __uint_as_float(((uint32)u) << 16); }
__device__ __forceinline__ uint32 packp(float a, float b){
    return (uint32)f2b(a) | ((uint32)f2b(b) << 16);
}
__device__ __forceinline__ float plo(uint32 u){ return __uint_as_float(u << 16); }
__device__ __forceinline__ float phi(uint32 u){ return __uint_as_float(u & 0xffff0000u); }
__device__ __forceinline__ float plerp(uint32 u, float f){ float a = plo(u); return fmaf(f, phi(u) - a, a); }
__device__ __forceinline__ float cutoff(float d){
    return (d < CUTV) ? 0.5f*(__cosf(d * 0.62831853071795864f) + 1.0f) : 0.0f;
}

// ---------------- setup mega-kernel: independent sections by blockIdx range ----------------
// sections: count | prep_nemb | pad | build_tables | build_ne | build_wt | build_bias
__global__ __launch_bounds__(256) void k_setup(
    const int* __restrict__ ei, int E, int* __restrict__ counts,
    const int* __restrict__ z, const float* __restrict__ ne_emb, ushort16* __restrict__ nemb16, int N,
    ushort16* __restrict__ hb16, ushort16* __restrict__ vecm, ushort16* __restrict__ xab16, int Nup, int N3up,
    const float* __restrict__ means, const float* __restrict__ betas,
    const float* __restrict__ dkW, const float* __restrict__ dkb,
    const float* __restrict__ dvW, const float* __restrict__ dvb, uint32* __restrict__ Tp,
    const float* __restrict__ dpW, const float* __restrict__ dpb, uint32* __restrict__ Tne32,
    const float* __restrict__ qW, const float* __restrict__ kW, const float* __restrict__ vW,
    const float* __restrict__ vecW, const float* __restrict__ oW, ushort16* __restrict__ WT,
    const float* __restrict__ kb, const float* __restrict__ vb, float* __restrict__ kvbias){
    __shared__ float ea_s[KB+1][NRBF+2];
    __shared__ float ne0[2][NRBF], ne1[2][NRBF];
    __shared__ ushort16 tws[128][33];
    int tid = threadIdx.x;
    int CB  = (E + 255) >> 8;
    int NPB = (N*HID + 255) >> 8;
    int b = blockIdx.x;
    if (b < CB){
        int e = b*256 + tid;
        if (e < E) atomicAdd(&counts[ei[E + e]], 1);
        return;
    }
    b -= CB;
    if (b < NPB){
        int idx = b*256 + tid;
        if (idx < N*HID){
            int n = idx >> 7, h = idx & 127;
            nemb16[idx] = f2b(ne_emb[(size_t)z[n]*HID + h]);
        }
        return;
    }
    b -= NPB;
    if (b < 64){
        int i = b*256 + tid;
        int hpad = (Nup - N)*HID;
        int vpad = (N3up - 3*N)*HID;
        if (i < hpad){ hb16[(size_t)N*HID + i] = 0; xab16[(size_t)N*HID + i] = 0; }
        if (i < vpad) vecm[(size_t)3*N*HID + i] = 0;
        return;
    }
    b -= 64;
    if (b < TB){
        int jb = (b % TBLK) * KB;
        int l  = b / TBLK;
        for (int idx = tid; idx < (KB+1)*NRBF; idx += 256){
            int kk = idx / NRBF, r = idx - kk*NRBF;
            float d = (jb + kk) * TINV;
            float u = __expf(-d) - means[r];
            ea_s[kk][r] = cutoff(d) * __expf(-betas[r]*u*u);
        }
        __syncthreads();
        #pragma unroll
        for (int half = 0; half < 2; half++){
            int c = tid + half*256;
            int h = c >> 2, i = c & 3;
            const float* Wcol; int stride; float bias;
            if (i == 0){
                Wcol = dkW + (size_t)l*NRBF*HID + h; stride = HID;
                bias = dkb[(size_t)l*HID + h];
            } else {
                int col = ((h >> 4)*48 + (h & 15)) + 16*(i-1);
                Wcol = dvW + (size_t)l*NRBF*384 + col; stride = 384;
                bias = dvb[(size_t)l*384 + col];
            }
            float a[KB+1];
            #pragma unroll
            for (int k = 0; k <= KB; k++) a[k] = bias;
            for (int r = 0; r < NRBF; r++){
                float w = Wcol[(size_t)r*stride];
                #pragma unroll
                for (int k = 0; k <= KB; k++) a[k] += ea_s[k][r]*w;
            }
            uint32* dst = Tp + (size_t)l*TSTRIDE + (size_t)jb*TRWORDS + c;
            float sp = siluf(a[0]);
            #pragma unroll
            for (int k = 0; k < KB; k++){
                int j = jb + k;
                if (j >= TROWS) break;
                float sn = siluf(a[k+1]);
                dst[(size_t)k*TRWORDS] = packp(sp, sn);
                sp = sn;
            }
        }
        return;
    }
    b -= TB;
    if (b < NEB){
        int half = tid >> 7, c = tid & 127;
        int j = b*2 + half;
        bool ok = (j < TROWS);
        if (ok && c < NRBF){
            float d0 = j * TINV, d1 = (j+1) * TINV;
            float m = means[c], be = betas[c];
            float u0 = __expf(-d0) - m, u1 = __expf(-d1) - m;
            ne0[half][c] = cutoff(d0) * __expf(-be*u0*u0);
            ne1[half][c] = cutoff(d1) * __expf(-be*u1*u1);
        }
        __syncthreads();
        if (ok){
            float c0 = cutoff(j * TINV), c1 = cutoff((j+1) * TINV);
            float a0 = dpb[c], a1 = a0;
            #pragma unroll
            for (int r = 0; r < NRBF; r++){
                float w = dpW[r*HID + c];
                a0 += ne0[half][r]*w; a1 += ne1[half][r]*w;
            }
            Tne32[(size_t)j*HID + c] = packp(a0*c0, a1*c1);
        }
        return;
    }
    b -= NEB;
    if (b < WTB){
        int l = b / (WCOLS/32);
        int c0 = (b % (WCOLS/32))*32;
        for (int i = tid; i < 128*32; i += 256){
            int k = i >> 5, c = i & 31;
            int gcol = c0 + c;
            const float* W; int C; int oc;
            if (gcol < 128)      { W = qW   + (size_t)l*HID*128; C = 128; oc = gcol; }
            else if (gcol < 640) {
                int s = gcol - 128; int h = s >> 2, si = s & 3;
                if (si == 3){ W = kW + (size_t)l*HID*128; C = 128; oc = h; }
                else        { W = vW + (size_t)l*HID*384; C = 384; oc = (h>>4)*48 + (h&15) + 16*si; }
            }
            else if (gcol < 1024){ W = vecW + (size_t)l*HID*384; C = 384; oc = gcol-640; }
            else                 { W = oW   + (size_t)l*HID*384; C = 384; oc = gcol-1024; }
            tws[k][c] = f2b(W[(size_t)k*C + oc]);
        }
        __syncthreads();
        ushort16* dst = WT + (size_t)l*WCOLS*HID + (size_t)c0*HID;
        for (int i = tid; i < 128*32; i += 256){
            int c = i >> 7, k = i & 127;
            dst[(size_t)c*HID + k] = tws[k][c];
        }
        return;
    }
    b -= WTB;
    {
        int l = b;
        #pragma unroll
        for (int half = 0; half < 2; half++){
            int s = tid + half*256;
            int h = s >> 2, i = s & 3;
            float v = (i == 3) ? kb[(size_t)l*HID + h]
                               : vb[(size_t)l*384 + (h>>4)*48 + (h&15) + 16*i];
            kvbias[(size_t)l*512 + s] = v;
        }
    }
}

// ---------------- counting sort chain ----------------
__global__ void k_scan(const int* counts, int* offsets, int* cursor, int n){
    __shared__ int part[1024];
    int tid = threadIdx.x;
    int PER = (n + 1023) >> 10;
    int base = tid * PER;
    int loc[8]; int s = 0;
    #pragma unroll 8
    for (int ii = 0; ii < 8; ii++){
        if (ii < PER){
            int idx = base + ii;
            int c = (idx < n) ? counts[idx] : 0;
            loc[ii] = s; s += c;
        }
    }
    part[tid] = s;
    __syncthreads();
    for (int off = 1; off < 1024; off <<= 1){
        int v = (tid >= off) ? part[tid - off] : 0;
        __syncthreads();
        part[tid] += v;
        __syncthreads();
    }
    int excl = (tid == 0) ? 0 : part[tid - 1];
    #pragma unroll 8
    for (int ii = 0; ii < 8; ii++){
        if (ii < PER){
            int idx = base + ii;
            if (idx < n){ int o = excl + loc[ii]; offsets[idx] = o; cursor[idx] = o; }
        }
    }
    if (tid == 1023) offsets[n] = part[1023];
}

__global__ void k_scatter(const int* ei, int E, int* cursor, int* eperm){
    int e = blockIdx.x*blockDim.x + threadIdx.x;
    if (e < E){
        int d = ei[E + e];
        int pos = atomicAdd(&cursor[d], 1);
        eperm[pos] = e;
    }
}

// src-sort each dst segment (64-chunks, rank by shuffle) + fused edge_vals
__global__ __launch_bounds__(256) void k_srcsort_vals(
    const int* offsets, const int* ei, const int* eperm, const float* edge_vec, int N,
    int4* edata, float4* evn4){
    int node = blockIdx.x*4 + (threadIdx.x >> 6);
    int lane = threadIdx.x & 63;
    if (node >= N) return;
    int r0 = offsets[node], r1 = offsets[node+1];
    for (int c0 = r0; c0 < r1; c0 += 64){
        int n = min(64, r1 - c0);
        int e = 0; int key = 0x7fffffff;
        if (lane < n){ e = eperm[c0 + lane]; key = ei[e]; }
        int rank = 0;
        for (int t = 0; t < n; t++){
            int kt = __shfl(key, t, 64);
            if (t != lane && ((kt < key) || (kt == key && t < lane))) rank++;
        }
        if (lane < n){
            int s = key;
            float vx = edge_vec[e*3+0], vy = edge_vec[e*3+1], vz = edge_vec[e*3+2];
            float ew = sqrtf(vx*vx + vy*vy + vz*vz);
            float cut = cutoff(ew);
            int ns = (s != node) ? 1 : 0;
            float inv = ns ? (1.0f/ew) : 1.0f;
            float un = fminf(ew * TSCALE, (float)KNOTS);
            int j = (int)un;
            float f = un - (float)j;
            int row = c0 + rank;
            int4 ed; ed.x = s; ed.y = j; ed.z = __float_as_int(f); ed.w = __float_as_int(cut);
            edata[row] = ed;
            float4 ev; ev.x = vx*inv; ev.y = vy*inv; ev.z = vz*inv; ev.w = ns ? 1.0f : 0.0f;
            evn4[row] = ev;
        }
    }
}

// ---------------- MFMA GEMM: merged q|kv|vecW, coalesced epilogue, compact grid ----------------
__global__ __launch_bounds__(256) void k_mfma01(
    const ushort16* __restrict__ hb16, const ushort16* __restrict__ vecm,
    const ushort16* __restrict__ WT, const float* __restrict__ qbias,
    const float* __restrict__ kvbias,
    float* __restrict__ qo, ushort16* __restrict__ vpack,
    ushort16* __restrict__ vecout, int N){
    int NT1 = (N + 63) >> 6;
    int NT3 = (3*N + 63) >> 6;
    int b = blockIdx.x;
    int cg, rblk;
    if (b < 10*NT1){ cg = b / NT1; rblk = (b - cg*NT1)*64; }
    else { int b2 = b - 10*NT1; int c2 = b2 / NT3; cg = 10 + c2; rblk = (b2 - c2*NT3)*64; }
    const ushort16* A; int R; int cblk; const ushort16* wt;
    if (cg < 10){ A = hb16; R = N;   cblk = cg*64;      wt = WT; }
    else        { A = vecm; R = 3*N; cblk = (cg-10)*64; wt = WT + (size_t)640*HID; }
    int wave = threadIdx.x >> 6, lane = threadIdx.x & 63;
    int r0 = rblk + wave*16;
    int l16 = lane & 15, lg = lane >> 4;
    short8 a[4];
    const ushort16* ar = A + (size_t)(r0 + l16)*HID + lg*8;
    #pragma unroll
    for (int ks = 0; ks < 4; ks++) a[ks] = *(const short8*)(ar + ks*32);
    f32x4 acc[4];
    #pragma unroll
    for (int ct = 0; ct < 4; ct++){ acc[ct][0]=0.f; acc[ct][1]=0.f; acc[ct][2]=0.f; acc[ct][3]=0.f; }
    #pragma unroll
    for (int ct = 0; ct < 4; ct++){
        const ushort16* br = wt + (size_t)(cblk + ct*16 + l16)*HID + lg*8;
        #pragma unroll
        for (int ks = 0; ks < 4; ks++){
            short8 bfr = *(const short8*)(br + ks*32);
            acc[ct] = __builtin_amdgcn_mfma_f32_16x16x32_bf16(a[ks], bfr, acc[ct], 0, 0, 0);
        }
    }
    __shared__ ushort16 lds[64][72];
    if (cg < 2){
        #pragma unroll
        for (int ct = 0; ct < 4; ct++){
            int gc = cblk + ct*16 + l16;
            float bb = qbias[gc];
            #pragma unroll
            for (int rg = 0; rg < 4; rg++){
                int row = r0 + lg*4 + rg;
                if (row < R) qo[(size_t)row*HID + gc] = acc[ct][rg] + bb;
            }
        }
        return;
    }
    const float* bias = (cg < 10) ? (kvbias + (cblk - 128)) : nullptr;
    #pragma unroll
    for (int ct = 0; ct < 4; ct++){
        int lc = ct*16 + l16;
        float bb = bias ? bias[lc] : 0.f;
        #pragma unroll
        for (int rg = 0; rg < 4; rg++)
            lds[wave*16 + lg*4 + rg][lc] = f2b(acc[ct][rg] + bb);
    }
    __syncthreads();
    ushort16* out; int stride, colbase;
    if (cg < 10){ out = vpack;  stride = 512; colbase = cblk - 128; }
    else        { out = vecout; stride = 384; colbase = cblk; }
    const uint32* l32 = (const uint32*)&lds[0][0];
    #pragma unroll
    for (int it = 0; it < 8; it++){
        int idx = it*256 + threadIdx.x;
        int row = idx >> 5, cp = idx & 31;
        int grow = rblk + row;
        if (grow < R){
            uint32 val = l32[row*36 + cp];
            *((uint32*)(out + (size_t)grow*stride + colbase) + cp) = val;
        }
    }
}

// ---------------- neighbor embedding (packed table + bf16 emb, 4-edge batch) ----------------
__global__ __launch_bounds__(128) void k_ne_agg(
    const int* __restrict__ offsets, const int4* __restrict__ edata,
    const uint32* __restrict__ Tne32, const ushort16* __restrict__ nemb16,
    float* __restrict__ agg){
    int i = blockIdx.x, h = threadIdx.x;
    float acc = 0.f;
    int r0 = offsets[i], r1 = offsets[i+1];
    for (int t0 = r0; t0 < r1; t0 += 4){
        uint32 tn_[4]; ushort16 nb_[4]; float f_[4]; int s_[4];
        #pragma unroll
        for (int u = 0; u < 4; u++){
            int row = min(t0 + u, r1 - 1);
            int4 ed = edata[row];
            s_[u] = ed.x;
            f_[u] = __int_as_float(ed.z);
            tn_[u] = Tne32[(size_t)ed.y*HID + h];
            nb_[u] = nemb16[(size_t)ed.x*HID + h];
        }
        #pragma unroll
        for (int u = 0; u < 4; u++){
            if (t0 + u >= r1) break;
            if (s_[u] != i) acc += plerp(tn_[u], f_[u]) * b2f(nb_[u]);
        }
    }
    agg[(size_t)i*HID + h] = acc;
}

// combine + LN(layer0) + zero vec state/mirrors; hb16 output
__global__ __launch_bounds__(128) void k_combine_ln(
    const int* z, const float* emb, const float* agg, const float* cbW, const float* cbb,
    const float* lnw0, const float* lnb0,
    float* x, ushort16* hb16, float* vec, ushort16* vecm, uint32* vecpack, int N){
    int n0 = blockIdx.x*8, h = threadIdx.x;
    __shared__ float in_s[8][2*HID];
    int nr = min(8, N - n0);
    for (int m = 0; m < nr; m++){
        in_s[m][h]       = emb[(size_t)z[n0+m]*HID + h];
        in_s[m][HID + h] = agg[(size_t)(n0+m)*HID + h];
    }
    __syncthreads();
    float acc[8];
    #pragma unroll
    for (int m = 0; m < 8; m++) acc[m] = 0.f;
    for (int kk = 0; kk < 2*HID; kk += 4){
        float w0 = cbW[(kk+0)*HID + h], w1 = cbW[(kk+1)*HID + h];
        float w2 = cbW[(kk+2)*HID + h], w3 = cbW[(kk+3)*HID + h];
        #pragma unroll
        for (int m = 0; m < 8; m++){
            const float* a = &in_s[m][kk];
            acc[m] += a[0]*w0 + a[1]*w1 + a[2]*w2 + a[3]*w3;
        }
    }
    float bias = cbb[h], w = lnw0[h], bb = lnb0[h];
    __shared__ float r1_[2], r2_[2];
    int wid = h >> 6;
    for (int m = 0; m < nr; m++){
        int n = n0 + m;
        float v = acc[m] + bias;
        x[(size_t)n*HID + h] = v;
        float s1 = v, s2 = v*v;
        #pragma unroll
        for (int o = 32; o; o >>= 1){ s1 += __shfl_xor(s1, o, 64); s2 += __shfl_xor(s2, o, 64); }
        if ((h & 63) == 0){ r1_[wid] = s1; r2_[wid] = s2; }
        __syncthreads();
        float sum = r1_[0] + r1_[1], sumsq = r2_[0] + r2_[1];
        float mean = sum * (1.f/HID);
        float var = sumsq * (1.f/HID) - mean*mean;
        float inv = rsqrtf(var + 1e-5f);
        hb16[(size_t)n*HID + h] = f2b((v - mean)*inv*w + bb);
        __syncthreads();
        vec [(size_t)n*384 + h]       = 0.f;
        vec [(size_t)n*384 + 128 + h] = 0.f;
        vec [(size_t)n*384 + 256 + h] = 0.f;
        vecm[(size_t)n*384 + h]       = 0;
        vecm[(size_t)n*384 + 128 + h] = 0;
        vecm[(size_t)n*384 + 256 + h] = 0;
        vecpack[(size_t)n*256 + 2*h]     = 0;
        vecpack[(size_t)n*256 + 2*h + 1] = 0;
    }
}

// ---------------- fused edge aggregation (r9 shape, 2 nodes per 256-thr block) ----------------
__global__ __launch_bounds__(256) void k_edge_agg(
    const int* __restrict__ offsets, const int4* __restrict__ edata,
    const float4* __restrict__ evn4, const uint32* __restrict__ Tp,
    const float* __restrict__ q, const ushort16* __restrict__ vpack,
    const uint32* __restrict__ vecpack,
    ushort16* __restrict__ xa16, float* __restrict__ va, int N){
    int i = blockIdx.x*2 + (threadIdx.x >> 7);
    int h = threadIdx.x & 127;
    if (i >= N) return;
    float qv = q[(size_t)i*HID + h];
    float axa = 0.f, av0 = 0.f, av1 = 0.f, av2 = 0.f;
    int r0 = offsets[i], r1 = offsets[i+1];
    for (int t0 = r0; t0 < r1; t0 += 4){
        float f_[4], cut_[4], ex_[4], ey_[4], ez_[4];
        uint4 t4_[4];
        uint2 vp_[4], vc_[4];
        #pragma unroll
        for (int u = 0; u < 4; u++){
            int row = min(t0 + u, r1 - 1);
            int4 ed = edata[row];
            int s = ed.x, j = ed.y;
            f_[u]   = __int_as_float(ed.z);
            cut_[u] = __int_as_float(ed.w);
            t4_[u] = *(const uint4*)(Tp + (size_t)j*TRWORDS + 4*h);
            vp_[u] = *(const uint2*)((const uint32*)(vpack + (size_t)s*512) + 2*h);
            vc_[u] = *(const uint2*)(vecpack + (size_t)s*256 + 2*h);
            float4 ev = evn4[row];
            ex_[u] = ev.x; ey_[u] = ev.y; ez_[u] = ev.z;
        }
        #pragma unroll
        for (int u = 0; u < 4; u++){
            if (t0 + u >= r1) break;
            float f = f_[u];
            float dk = plerp(t4_[u].x, f);
            float kv = phi(vp_[u].y);
            float p = qv * kv * dk;
            p += __shfl_xor(p, 1, 64);
            p += __shfl_xor(p, 2, 64);
            p += __shfl_xor(p, 4, 64);
            p += __shfl_xor(p, 8, 64);
            float attn = siluf(p) * cut_[u];
            float dv0 = plerp(t4_[u].y, f);
            float dv1 = plerp(t4_[u].z, f);
            float dv2 = plerp(t4_[u].w, f);
            axa += plo(vp_[u].x) * dv0 * attn;
            float w1v = phi(vp_[u].x) * dv1;
            float w2v = plo(vp_[u].y) * dv2;
            av0 += plo(vc_[u].x)*w1v + w2v*ex_[u];
            av1 += phi(vc_[u].x)*w1v + w2v*ey_[u];
            av2 += plo(vc_[u].y)*w1v + w2v*ez_[u];
        }
    }
    xa16[(size_t)i*HID + h] = f2b(axa);
    va[(size_t)i*384 + h]       = av0;
    va[(size_t)i*384 + 128 + h] = av1;
    va[(size_t)i*384 + 256 + h] = av2;
}

// ---------------- fused oW GEMM + vecdot + residual update + next-layer LN ----------------
#define OROWS 32
__global__ __launch_bounds__(256) void k_oupd(
    const ushort16* __restrict__ xab16, const ushort16* __restrict__ WT,
    const float* __restrict__ obias,
    float* __restrict__ x, float* __restrict__ vec, ushort16* __restrict__ vecm,
    uint32* __restrict__ vecpack,
    const ushort16* __restrict__ vecout, const float* __restrict__ va,
    const float* __restrict__ lnw_n, const float* __restrict__ lnb_n,
    ushort16* __restrict__ hb16, float* __restrict__ outx, float* __restrict__ outv,
    int N, int fin){
    __shared__ float o_s[OROWS][385];
    int tile = blockIdx.x; int r0 = tile*OROWS;
    int wid = threadIdx.x >> 6, lane = threadIdx.x & 63;
    int l16 = lane & 15, lg = lane >> 4;
    {
        int rr = r0 + (wid & 1)*16;
        const ushort16* ar = xab16 + (size_t)(rr + l16)*HID + lg*8;
        short8 a[4];
        #pragma unroll
        for (int ks = 0; ks < 4; ks++) a[ks] = *(const short8*)(ar + ks*32);
        int cbase = (wid >> 1)*192;
        const ushort16* wt = WT + (size_t)1024*HID;
        #pragma unroll
        for (int ct = 0; ct < 12; ct++){
            f32x4 acc; acc[0]=0.f; acc[1]=0.f; acc[2]=0.f; acc[3]=0.f;
            const ushort16* br = wt + (size_t)(cbase + ct*16 + l16)*HID + lg*8;
            #pragma unroll
            for (int ks = 0; ks < 4; ks++){
                short8 b = *(const short8*)(br + ks*32);
                acc = __builtin_amdgcn_mfma_f32_16x16x32_bf16(a[ks], b, acc, 0, 0, 0);
            }
            int gc = cbase + ct*16 + l16;
            float bb = obias[gc];
            #pragma unroll
            for (int rg = 0; rg < 4; rg++)
                o_s[(wid & 1)*16 + lg*4 + rg][gc] = acc[rg] + bb;
        }
    }
    __syncthreads();
    for (int pass = 0; pass < 8; pass++){
        int nrow = pass*4 + wid;
        int n = r0 + nrow;
        if (n >= N) break;
        const ushort16* vo = vecout + (size_t)n*1152;
        const float* o_r = o_s[nrow];
        size_t vb = (size_t)n*384;
        float xva, xvb, v0a, v0b, v1a, v1b, v2a, v2b;
        #pragma unroll
        for (int half = 0; half < 2; half++){
            int hh = lane + half*64;
            float vdot = b2f(vo[hh])*b2f(vo[128+hh]) + b2f(vo[384+hh])*b2f(vo[512+hh])
                       + b2f(vo[768+hh])*b2f(vo[896+hh]);
            float o1 = o_r[hh], o2 = o_r[128+hh], o3 = o_r[256+hh];
            float xv = x[(size_t)n*HID + hh] + vdot*o2 + o3;
            float v0 = vec[vb + hh]       + b2f(vo[256  + hh])*o1 + va[vb + hh];
            float v1 = vec[vb + 128 + hh] + b2f(vo[640  + hh])*o1 + va[vb + 128 + hh];
            float v2 = vec[vb + 256 + hh] + b2f(vo[1024 + hh])*o1 + va[vb + 256 + hh];
            if (half == 0){ xva = xv; v0a = v0; v1a = v1; v2a = v2; }
            else          { xvb = xv; v0b = v0; v1b = v1; v2b = v2; }
        }
        float s1 = xva + xvb, s2 = xva*xva + xvb*xvb;
        #pragma unroll
        for (int o = 32; o; o >>= 1){ s1 += __shfl_xor(s1, o, 64); s2 += __shfl_xor(s2, o, 64); }
        float mean = s1 * (1.f/HID);
        float var = s2 * (1.f/HID) - mean*mean;
        float inv = rsqrtf(var + 1e-5f);
        #pragma unroll
        for (int half = 0; half < 2; half++){
            int hh = lane + half*64;
            float xv = half ? xvb : xva;
            float v0 = half ? v0b : v0a;
            float v1 = half ? v1b : v1a;
            float v2 = half ? v2b : v2a;
            float lnv = (xv - mean)*inv*lnw_n[hh] + lnb_n[hh];
            if (!fin){
                x[(size_t)n*HID + hh] = xv;
                vec[vb + hh] = v0; vec[vb + 128 + hh] = v1; vec[vb + 256 + hh] = v2;
                vecm[vb + hh] = f2b(v0); vecm[vb + 128 + hh] = f2b(v1); vecm[vb + 256 + hh] = f2b(v2);
                vecpack[(size_t)n*256 + 2*hh]     = packp(v0, v1);
                vecpack[(size_t)n*256 + 2*hh + 1] = packp(v2, 0.f);
                hb16[(size_t)n*HID + hh] = f2b(lnv);
            } else {
                outx[(size_t)n*HID + hh] = lnv;
                outv[vb + hh] = v0; outv[vb + 128 + hh] = v1; outv[vb + 256 + hh] = v2;
            }
        }
    }
}

// ---------------- host ----------------
extern "C" void kernel_launch(void* const* d_in, const int* in_sizes, int n_in,
                              void* d_out, int out_size, void* d_ws, size_t ws_size,
                              hipStream_t stream){
    const int*   z        = (const int*)  d_in[0];
    const int*   ei       = (const int*)  d_in[1];
    const float* edge_vec = (const float*)d_in[2];
    const float* emb      = (const float*)d_in[3];
    const float* means    = (const float*)d_in[4];
    const float* betas    = (const float*)d_in[5];
    const float* ne_emb   = (const float*)d_in[6];
    const float* dpW      = (const float*)d_in[7];
    const float* dpb      = (const float*)d_in[8];
    const float* cbW      = (const float*)d_in[9];
    const float* cbb      = (const float*)d_in[10];
    const float* lnw      = (const float*)d_in[11];
    const float* lnb      = (const float*)d_in[12];
    const float* qW       = (const float*)d_in[13];
    const float* qb       = (const float*)d_in[14];
    const float* kW       = (const float*)d_in[15];
    const float* kb       = (const float*)d_in[16];
    const float* vW       = (const float*)d_in[17];
    const float* vb       = (const float*)d_in[18];
    const float* oW       = (const float*)d_in[19];
    const float* obias    = (const float*)d_in[20];
    const float* vecW     = (const float*)d_in[21];
    const float* dkW      = (const float*)d_in[22];
    const float* dkb      = (const float*)d_in[23];
    const float* dvW      = (const float*)d_in[24];
    const float* dvb      = (const float*)d_in[25];
    const float* onw      = (const float*)d_in[26];
    const float* onb      = (const float*)d_in[27];

    int N = in_sizes[0];
    int E = in_sizes[1] / 2;
    int Nup  = ((N + 63) >> 6) << 6;
    int N3up = ((3*N + 63) >> 6) << 6;

    char* p = (char*)d_ws;
    auto alloc = [&](size_t bytes){ void* r = (void*)p; p += (bytes + 255) & ~(size_t)255; return r; };
    int*      counts  = (int*)     alloc((size_t)N*4);
    int*      offsets = (int*)     alloc((size_t)(N+1)*4);
    int*      cursor  = (int*)     alloc((size_t)N*4);
    int*      eperm   = (int*)     alloc((size_t)E*4);
    int4*     edata   = (int4*)    alloc((size_t)E*16);
    float4*   evn4    = (float4*)  alloc((size_t)E*16);
    uint32*   Tp      = (uint32*)  alloc((size_t)NLAYERS*TSTRIDE*4);
    uint32*   Tne32   = (uint32*)  alloc((size_t)TROWS*HID*4);
    ushort16* WT      = (ushort16*)alloc((size_t)NLAYERS*WCOLS*HID*2);
    float*    kvbias  = (float*)   alloc((size_t)NLAYERS*512*4);
    ushort16* nemb16  = (ushort16*)alloc((size_t)N*HID*2);
    float*    agg     = (float*)   alloc((size_t)N*HID*4);
    float*    xb      = (float*)   alloc((size_t)N*HID*4);
    ushort16* hb16    = (ushort16*)alloc((size_t)Nup*HID*2);
    float*    qb_     = (float*)   alloc((size_t)N*HID*4);
    ushort16* vpack   = (ushort16*)alloc((size_t)N*512*2);
    uint32*   vecpack = (uint32*)  alloc((size_t)N*256*4);
    ushort16* vecm    = (ushort16*)alloc((size_t)N3up*HID*2);
    float*    vecb    = (float*)   alloc((size_t)N*384*4);
    ushort16* vecout  = (ushort16*)alloc((size_t)N*1152*2);
    ushort16* xab16   = (ushort16*)alloc((size_t)Nup*HID*2);
    float*    vab     = (float*)   alloc((size_t)N*384*4);

    hipMemsetAsync(counts, 0, (size_t)N*4, stream);

    int CB  = (E + 255) >> 8;
    int NPB = (N*HID + 255) >> 8;
    int setup_blocks = CB + NPB + 64 + TB + NEB + WTB + NLAYERS;
    k_setup<<<setup_blocks, 256, 0, stream>>>(
        ei, E, counts,
        z, ne_emb, nemb16, N,
        hb16, vecm, xab16, Nup, N3up,
        means, betas, dkW, dkb, dvW, dvb, Tp,
        dpW, dpb, Tne32,
        qW, kW, vW, vecW, oW, WT,
        kb, vb, kvbias);
    k_scan<<<1, 1024, 0, stream>>>(counts, offsets, cursor, N);
    k_scatter<<<(E+255)/256, 256, 0, stream>>>(ei, E, cursor, eperm);
    k_srcsort_vals<<<(N+3)/4, 256, 0, stream>>>(offsets, ei, eperm, edge_vec, N, edata, evn4);
    k_ne_agg<<<N, 128, 0, stream>>>(offsets, edata, Tne32, nemb16, agg);
    k_combine_ln<<<(N+7)/8, 128, 0, stream>>>(z, emb, agg, cbW, cbb, lnw, lnb,
                                              xb, hb16, vecb, vecm, vecpack, N);

    float* outx = (float*)d_out;
    float* outv = (float*)d_out + (size_t)N*HID;

    int NT1 = (N + 63) >> 6;
    int NT3 = (3*N + 63) >> 6;
    for (int l = 0; l < NLAYERS; l++){
        const ushort16* WTl = WT + (size_t)l*WCOLS*HID;
        k_mfma01<<<10*NT1 + 6*NT3, 256, 0, stream>>>(hb16, vecm, WTl,
            qb + (size_t)l*HID, kvbias + (size_t)l*512,
            qb_, vpack, vecout, N);
        k_edge_agg<<<(N+1)/2, 256, 0, stream>>>(offsets, edata, evn4, Tp + (size_t)l*TSTRIDE,
                                                qb_, vpack, vecpack, xab16, vab, N);
        int fin = (l == NLAYERS-1);
        k_oupd<<<(N + OROWS - 1)/OROWS, 256, 0, stream>>>(xab16, WTl, obias + (size_t)l*384,
            xb, vecb, vecm, vecpack, vecout, vab,
            fin ? onw : lnw + (size_t)(l+1)*HID,
            fin ? onb : lnb + (size_t)(l+1)*HID,
            hb16, outx, outv, N, fin);
    }
}

// Round 14
// 607.529 us; speedup vs baseline: 1.1502x; 1.1502x over previous
//
#include <hip/hip_runtime.h>
#include <math.h>

#define HID 128
#define NRBF 50
#define NLAYERS 6
#define CUTV 5.0f
#define KNOTS 1024            // intervals
#define TSCALE 204.8f         // KNOTS / CUTV
#define TINV   0.0048828125f  // CUTV / KNOTS
#define TROWS  (KNOTS + 1)    // paired rows j=0..KNOTS
#define TRWORDS 512           // [h][4]: {dk, dv0, dv1, dv2} paired-bf16 words
#define TSTRIDE ((size_t)TROWS * TRWORDS)
#define WCOLS 1408            // 128 q | 512 kv-permuted | 384 vecW | 384 oW
#define KB 16                 // knot-pairs per table-build block

typedef unsigned int  uint32;
typedef unsigned short ushort16;
typedef __attribute__((ext_vector_type(8))) short short8;
typedef __attribute__((ext_vector_type(4))) float f32x4;

__device__ __forceinline__ float siluf(float x){ return x / (1.0f + __expf(-x)); }
__device__ __forceinline__ float lerpf(float a, float b, float f){ return fmaf(f, b - a, a); }
__device__ __forceinline__ ushort16 f2b(float x){
    uint32 u = __float_as_uint(x);
    u += 0x7fffu + ((u >> 16) & 1u);
    return (ushort16)(u >> 16);
}
__device__ __forceinline__ float b2f(ushort16 u){ return __uint_as_float(((uint32)u) << 16); }
__device__ __forceinline__ uint32 packp(float a, float b){
    return (uint32)f2b(a) | ((uint32)f2b(b) << 16);
}
__device__ __forceinline__ float plo(uint32 u){ return __uint_as_float(u << 16); }
__device__ __forceinline__ float phi(uint32 u){ return __uint_as_float(u & 0xffff0000u); }
__device__ __forceinline__ float plerp(uint32 u, float f){ float a = plo(u); return fmaf(f, phi(u) - a, a); }
__device__ __forceinline__ float cutoff(float d){
    return (d < CUTV) ? 0.5f*(__cosf(d * 0.62831853071795864f) + 1.0f) : 0.0f;
}

// ---------------- light setup mega-kernel (zero LDS): count | prep_nemb | pad | bias ----------------
__global__ __launch_bounds__(256) void k_setup_light(
    const int* __restrict__ ei, int E, int* __restrict__ counts,
    const int* __restrict__ z, const float* __restrict__ ne_emb, ushort16* __restrict__ nemb16, int N,
    ushort16* __restrict__ hb16, ushort16* __restrict__ vecm, ushort16* __restrict__ xab16,
    int Nup, int N3up,
    const float* __restrict__ kb, const float* __restrict__ vb, float* __restrict__ kvbias){
    int tid = threadIdx.x;
    int CB  = (E + 255) >> 8;
    int NPB = (N*HID + 255) >> 8;
    int b = blockIdx.x;
    if (b < CB){
        int e = b*256 + tid;
        if (e < E) atomicAdd(&counts[ei[E + e]], 1);
        return;
    }
    b -= CB;
    if (b < NPB){
        int idx = b*256 + tid;
        if (idx < N*HID){
            int n = idx >> 7, h = idx & 127;
            nemb16[idx] = f2b(ne_emb[(size_t)z[n]*HID + h]);
        }
        return;
    }
    b -= NPB;
    if (b < 64){
        int i = b*256 + tid;
        int hpad = (Nup - N)*HID;
        int vpad = (N3up - 3*N)*HID;
        if (i < hpad){ hb16[(size_t)N*HID + i] = 0; xab16[(size_t)N*HID + i] = 0; }
        if (i < vpad) vecm[(size_t)3*N*HID + i] = 0;
        return;
    }
    b -= 64;
    {
        int l = b;
        #pragma unroll
        for (int half = 0; half < 2; half++){
            int s = tid + half*256;
            int h = s >> 2, i = s & 3;
            float v = (i == 3) ? kb[(size_t)l*HID + h]
                               : vb[(size_t)l*384 + (h>>4)*48 + (h&15) + 16*i];
            kvbias[(size_t)l*512 + s] = v;
        }
    }
}

// ---------------- counting sort chain ----------------
__global__ void k_scan(const int* counts, int* offsets, int* cursor, int n){
    __shared__ int part[1024];
    int tid = threadIdx.x;
    int PER = (n + 1023) >> 10;
    int base = tid * PER;
    int loc[8]; int s = 0;
    #pragma unroll 8
    for (int ii = 0; ii < 8; ii++){
        if (ii < PER){
            int idx = base + ii;
            int c = (idx < n) ? counts[idx] : 0;
            loc[ii] = s; s += c;
        }
    }
    part[tid] = s;
    __syncthreads();
    for (int off = 1; off < 1024; off <<= 1){
        int v = (tid >= off) ? part[tid - off] : 0;
        __syncthreads();
        part[tid] += v;
        __syncthreads();
    }
    int excl = (tid == 0) ? 0 : part[tid - 1];
    #pragma unroll 8
    for (int ii = 0; ii < 8; ii++){
        if (ii < PER){
            int idx = base + ii;
            if (idx < n){ int o = excl + loc[ii]; offsets[idx] = o; cursor[idx] = o; }
        }
    }
    if (tid == 1023) offsets[n] = part[1023];
}

__global__ void k_scatter(const int* ei, int E, int* cursor, int* eperm){
    int e = blockIdx.x*blockDim.x + threadIdx.x;
    if (e < E){
        int d = ei[E + e];
        int pos = atomicAdd(&cursor[d], 1);
        eperm[pos] = e;
    }
}

// src-sort each dst segment (64-chunks, rank by shuffle) + fused edge_vals
__global__ __launch_bounds__(256) void k_srcsort_vals(
    const int* offsets, const int* ei, const int* eperm, const float* edge_vec, int N,
    int4* edata, float4* evn4){
    int node = blockIdx.x*4 + (threadIdx.x >> 6);
    int lane = threadIdx.x & 63;
    if (node >= N) return;
    int r0 = offsets[node], r1 = offsets[node+1];
    for (int c0 = r0; c0 < r1; c0 += 64){
        int n = min(64, r1 - c0);
        int e = 0; int key = 0x7fffffff;
        if (lane < n){ e = eperm[c0 + lane]; key = ei[e]; }
        int rank = 0;
        for (int t = 0; t < n; t++){
            int kt = __shfl(key, t, 64);
            if (t != lane && ((kt < key) || (kt == key && t < lane))) rank++;
        }
        if (lane < n){
            int s = key;
            float vx = edge_vec[e*3+0], vy = edge_vec[e*3+1], vz = edge_vec[e*3+2];
            float ew = sqrtf(vx*vx + vy*vy + vz*vz);
            float cut = cutoff(ew);
            int ns = (s != node) ? 1 : 0;
            float inv = ns ? (1.0f/ew) : 1.0f;
            float un = fminf(ew * TSCALE, (float)KNOTS);
            int j = (int)un;
            float f = un - (float)j;
            int row = c0 + rank;
            int4 ed; ed.x = s; ed.y = j; ed.z = __float_as_int(f); ed.w = __float_as_int(cut);
            edata[row] = ed;
            float4 ev; ev.x = vx*inv; ev.y = vy*inv; ev.z = vz*inv; ev.w = ns ? 1.0f : 0.0f;
            evn4[row] = ev;
        }
    }
}

// ---------------- tables: knot-blocked build ----------------
// Row layout: slot 4h+0 = dk col h; slot 4h+1+i = dv col ((h>>4)*48 + (h&15) + 16*i)
__global__ __launch_bounds__(512) void k_build_tables(
    const float* means, const float* betas,
    const float* dkW, const float* dkb, const float* dvW, const float* dvb,
    uint32* Tp){
    int jb = blockIdx.x * KB;
    int l  = blockIdx.y;
    int c  = threadIdx.x;
    __shared__ float ea_s[KB+1][NRBF+2];
    for (int idx = c; idx < (KB+1)*NRBF; idx += 512){
        int kk = idx / NRBF, r = idx - kk*NRBF;
        float d = (jb + kk) * TINV;
        float u = __expf(-d) - means[r];
        ea_s[kk][r] = cutoff(d) * __expf(-betas[r]*u*u);
    }
    __syncthreads();
    int h = c >> 2, i = c & 3;
    const float* Wcol; int stride; float bias;
    if (i == 0){
        Wcol = dkW + (size_t)l*NRBF*HID + h; stride = HID;
        bias = dkb[(size_t)l*HID + h];
    } else {
        int col = ((h >> 4)*48 + (h & 15)) + 16*(i-1);
        Wcol = dvW + (size_t)l*NRBF*384 + col; stride = 384;
        bias = dvb[(size_t)l*384 + col];
    }
    float a[KB+1];
    #pragma unroll
    for (int k = 0; k <= KB; k++) a[k] = bias;
    for (int r = 0; r < NRBF; r++){
        float w = Wcol[(size_t)r*stride];
        #pragma unroll
        for (int k = 0; k <= KB; k++) a[k] += ea_s[k][r]*w;
    }
    uint32* dst = Tp + (size_t)l*TSTRIDE + (size_t)jb*TRWORDS + c;
    float sp = siluf(a[0]);
    #pragma unroll
    for (int k = 0; k < KB; k++){
        int j = jb + k;
        if (j >= TROWS) break;
        float sn = siluf(a[k+1]);
        dst[(size_t)k*TRWORDS] = packp(sp, sn);
        sp = sn;
    }
}

// NE table: paired bf16 in u32
__global__ __launch_bounds__(128) void k_build_ne(
    const float* means, const float* betas,
    const float* dpW, const float* dpb, uint32* Tne32){
    int j = blockIdx.x, c = threadIdx.x;
    __shared__ float ea0[NRBF], ea1[NRBF];
    float d0 = j * TINV, d1 = (j+1) * TINV;
    float c0 = cutoff(d0), c1 = cutoff(d1);
    if (c < NRBF){
        float m = means[c], be = betas[c];
        float u0 = __expf(-d0) - m, u1 = __expf(-d1) - m;
        ea0[c] = c0 * __expf(-be*u0*u0);
        ea1[c] = c1 * __expf(-be*u1*u1);
    }
    __syncthreads();
    float a0 = dpb[c], a1 = a0;
    #pragma unroll
    for (int r = 0; r < NRBF; r++){ float w = dpW[r*HID + c]; a0 += ea0[r]*w; a1 += ea1[r]*w; }
    Tne32[(size_t)j*HID + c] = packp(a0*c0, a1*c1);
}

// ---------------- weight transpose: WT[l][col][k] bf16 ----------------
__global__ __launch_bounds__(256) void k_build_wt(
    const float* qW, const float* kW, const float* vW, const float* vecW, const float* oW,
    ushort16* WT){
    int l = blockIdx.y; int c0 = blockIdx.x*32;
    __shared__ ushort16 t[128][33];
    for (int i = threadIdx.x; i < 128*32; i += 256){
        int k = i >> 5, c = i & 31;
        int gcol = c0 + c;
        const float* W; int C; int oc;
        if (gcol < 128)      { W = qW   + (size_t)l*HID*128; C = 128; oc = gcol; }
        else if (gcol < 640) {
            int s = gcol - 128; int h = s >> 2, si = s & 3;
            if (si == 3){ W = kW + (size_t)l*HID*128; C = 128; oc = h; }
            else        { W = vW + (size_t)l*HID*384; C = 384; oc = (h>>4)*48 + (h&15) + 16*si; }
        }
        else if (gcol < 1024){ W = vecW + (size_t)l*HID*384; C = 384; oc = gcol-640; }
        else                 { W = oW   + (size_t)l*HID*384; C = 384; oc = gcol-1024; }
        t[k][c] = f2b(W[(size_t)k*C + oc]);
    }
    __syncthreads();
    ushort16* dst = WT + (size_t)l*WCOLS*HID + (size_t)c0*HID;
    for (int i = threadIdx.x; i < 128*32; i += 256){
        int c = i >> 7, k = i & 127;
        dst[(size_t)c*HID + k] = t[k][c];
    }
}

// ---------------- MFMA GEMM: merged q|kv|vecW, coalesced epilogue, compact grid ----------------
__global__ __launch_bounds__(256) void k_mfma01(
    const ushort16* __restrict__ hb16, const ushort16* __restrict__ vecm,
    const ushort16* __restrict__ WT, const float* __restrict__ qbias,
    const float* __restrict__ kvbias,
    float* __restrict__ qo, ushort16* __restrict__ vpack,
    ushort16* __restrict__ vecout, int N){
    int NT1 = (N + 63) >> 6;
    int NT3 = (3*N + 63) >> 6;
    int b = blockIdx.x;
    int cg, rblk;
    if (b < 10*NT1){ cg = b / NT1; rblk = (b - cg*NT1)*64; }
    else { int b2 = b - 10*NT1; int c2 = b2 / NT3; cg = 10 + c2; rblk = (b2 - c2*NT3)*64; }
    const ushort16* A; int R; int cblk; const ushort16* wt;
    if (cg < 10){ A = hb16; R = N;   cblk = cg*64;      wt = WT; }
    else        { A = vecm; R = 3*N; cblk = (cg-10)*64; wt = WT + (size_t)640*HID; }
    int wave = threadIdx.x >> 6, lane = threadIdx.x & 63;
    int r0 = rblk + wave*16;
    int l16 = lane & 15, lg = lane >> 4;
    short8 a[4];
    const ushort16* ar = A + (size_t)(r0 + l16)*HID + lg*8;
    #pragma unroll
    for (int ks = 0; ks < 4; ks++) a[ks] = *(const short8*)(ar + ks*32);
    f32x4 acc[4];
    #pragma unroll
    for (int ct = 0; ct < 4; ct++){ acc[ct][0]=0.f; acc[ct][1]=0.f; acc[ct][2]=0.f; acc[ct][3]=0.f; }
    #pragma unroll
    for (int ct = 0; ct < 4; ct++){
        const ushort16* br = wt + (size_t)(cblk + ct*16 + l16)*HID + lg*8;
        #pragma unroll
        for (int ks = 0; ks < 4; ks++){
            short8 bfr = *(const short8*)(br + ks*32);
            acc[ct] = __builtin_amdgcn_mfma_f32_16x16x32_bf16(a[ks], bfr, acc[ct], 0, 0, 0);
        }
    }
    __shared__ ushort16 lds[64][72];
    if (cg < 2){
        #pragma unroll
        for (int ct = 0; ct < 4; ct++){
            int gc = cblk + ct*16 + l16;
            float bb = qbias[gc];
            #pragma unroll
            for (int rg = 0; rg < 4; rg++){
                int row = r0 + lg*4 + rg;
                if (row < R) qo[(size_t)row*HID + gc] = acc[ct][rg] + bb;
            }
        }
        return;
    }
    const float* bias = (cg < 10) ? (kvbias + (cblk - 128)) : nullptr;
    #pragma unroll
    for (int ct = 0; ct < 4; ct++){
        int lc = ct*16 + l16;
        float bb = bias ? bias[lc] : 0.f;
        #pragma unroll
        for (int rg = 0; rg < 4; rg++)
            lds[wave*16 + lg*4 + rg][lc] = f2b(acc[ct][rg] + bb);
    }
    __syncthreads();
    ushort16* out; int stride, colbase;
    if (cg < 10){ out = vpack;  stride = 512; colbase = cblk - 128; }
    else        { out = vecout; stride = 384; colbase = cblk; }
    const uint32* l32 = (const uint32*)&lds[0][0];
    #pragma unroll
    for (int it = 0; it < 8; it++){
        int idx = it*256 + threadIdx.x;
        int row = idx >> 5, cp = idx & 31;
        int grow = rblk + row;
        if (grow < R){
            uint32 val = l32[row*36 + cp];
            *((uint32*)(out + (size_t)grow*stride + colbase) + cp) = val;
        }
    }
}

// ---------------- neighbor embedding (packed table + bf16 emb, 4-edge batch) ----------------
__global__ __launch_bounds__(128) void k_ne_agg(
    const int* __restrict__ offsets, const int4* __restrict__ edata,
    const uint32* __restrict__ Tne32, const ushort16* __restrict__ nemb16,
    float* __restrict__ agg){
    int i = blockIdx.x, h = threadIdx.x;
    float acc = 0.f;
    int r0 = offsets[i], r1 = offsets[i+1];
    for (int t0 = r0; t0 < r1; t0 += 4){
        uint32 tn_[4]; ushort16 nb_[4]; float f_[4]; int s_[4];
        #pragma unroll
        for (int u = 0; u < 4; u++){
            int row = min(t0 + u, r1 - 1);
            int4 ed = edata[row];
            s_[u] = ed.x;
            f_[u] = __int_as_float(ed.z);
            tn_[u] = Tne32[(size_t)ed.y*HID + h];
            nb_[u] = nemb16[(size_t)ed.x*HID + h];
        }
        #pragma unroll
        for (int u = 0; u < 4; u++){
            if (t0 + u >= r1) break;
            if (s_[u] != i) acc += plerp(tn_[u], f_[u]) * b2f(nb_[u]);
        }
    }
    agg[(size_t)i*HID + h] = acc;
}

// combine + LN(layer0) + zero vec state/mirrors; hb16 output
__global__ __launch_bounds__(128) void k_combine_ln(
    const int* z, const float* emb, const float* agg, const float* cbW, const float* cbb,
    const float* lnw0, const float* lnb0,
    float* x, ushort16* hb16, float* vec, ushort16* vecm, uint32* vecpack, int N){
    int n0 = blockIdx.x*8, h = threadIdx.x;
    __shared__ float in_s[8][2*HID];
    int nr = min(8, N - n0);
    for (int m = 0; m < nr; m++){
        in_s[m][h]       = emb[(size_t)z[n0+m]*HID + h];
        in_s[m][HID + h] = agg[(size_t)(n0+m)*HID + h];
    }
    __syncthreads();
    float acc[8];
    #pragma unroll
    for (int m = 0; m < 8; m++) acc[m] = 0.f;
    for (int kk = 0; kk < 2*HID; kk += 4){
        float w0 = cbW[(kk+0)*HID + h], w1 = cbW[(kk+1)*HID + h];
        float w2 = cbW[(kk+2)*HID + h], w3 = cbW[(kk+3)*HID + h];
        #pragma unroll
        for (int m = 0; m < 8; m++){
            const float* a = &in_s[m][kk];
            acc[m] += a[0]*w0 + a[1]*w1 + a[2]*w2 + a[3]*w3;
        }
    }
    float bias = cbb[h], w = lnw0[h], bb = lnb0[h];
    __shared__ float r1_[2], r2_[2];
    int wid = h >> 6;
    for (int m = 0; m < nr; m++){
        int n = n0 + m;
        float v = acc[m] + bias;
        x[(size_t)n*HID + h] = v;
        float s1 = v, s2 = v*v;
        #pragma unroll
        for (int o = 32; o; o >>= 1){ s1 += __shfl_xor(s1, o, 64); s2 += __shfl_xor(s2, o, 64); }
        if ((h & 63) == 0){ r1_[wid] = s1; r2_[wid] = s2; }
        __syncthreads();
        float sum = r1_[0] + r1_[1], sumsq = r2_[0] + r2_[1];
        float mean = sum * (1.f/HID);
        float var = sumsq * (1.f/HID) - mean*mean;
        float inv = rsqrtf(var + 1e-5f);
        hb16[(size_t)n*HID + h] = f2b((v - mean)*inv*w + bb);
        __syncthreads();
        vec [(size_t)n*384 + h]       = 0.f;
        vec [(size_t)n*384 + 128 + h] = 0.f;
        vec [(size_t)n*384 + 256 + h] = 0.f;
        vecm[(size_t)n*384 + h]       = 0;
        vecm[(size_t)n*384 + 128 + h] = 0;
        vecm[(size_t)n*384 + 256 + h] = 0;
        vecpack[(size_t)n*256 + 2*h]     = 0;
        vecpack[(size_t)n*256 + 2*h + 1] = 0;
    }
}

// ---------------- fused edge aggregation (round-9 optimum: 5 packed loads/edge) ----------------
__global__ __launch_bounds__(128) void k_edge_agg(
    const int* __restrict__ offsets, const int4* __restrict__ edata,
    const float4* __restrict__ evn4, const uint32* __restrict__ Tp,
    const float* __restrict__ q, const ushort16* __restrict__ vpack,
    const uint32* __restrict__ vecpack,
    ushort16* __restrict__ xa16, float* __restrict__ va){
    int i = blockIdx.x, h = threadIdx.x;
    float qv = q[(size_t)i*HID + h];
    float axa = 0.f, av0 = 0.f, av1 = 0.f, av2 = 0.f;
    int r0 = offsets[i], r1 = offsets[i+1];
    for (int t0 = r0; t0 < r1; t0 += 4){
        float f_[4], cut_[4], ex_[4], ey_[4], ez_[4];
        uint4 t4_[4];
        uint2 vp_[4], vc_[4];
        #pragma unroll
        for (int u = 0; u < 4; u++){
            int row = min(t0 + u, r1 - 1);
            int4 ed = edata[row];
            int s = ed.x, j = ed.y;
            f_[u]   = __int_as_float(ed.z);
            cut_[u] = __int_as_float(ed.w);
            t4_[u] = *(const uint4*)(Tp + (size_t)j*TRWORDS + 4*h);
            vp_[u] = *(const uint2*)((const uint32*)(vpack + (size_t)s*512) + 2*h);
            vc_[u] = *(const uint2*)(vecpack + (size_t)s*256 + 2*h);
            float4 ev = evn4[row];
            ex_[u] = ev.x; ey_[u] = ev.y; ez_[u] = ev.z;
        }
        #pragma unroll
        for (int u = 0; u < 4; u++){
            if (t0 + u >= r1) break;
            float f = f_[u];
            float dk = plerp(t4_[u].x, f);
            float kv = phi(vp_[u].y);
            float p = qv * kv * dk;
            p += __shfl_xor(p, 1, 64);
            p += __shfl_xor(p, 2, 64);
            p += __shfl_xor(p, 4, 64);
            p += __shfl_xor(p, 8, 64);
            float attn = siluf(p) * cut_[u];
            float dv0 = plerp(t4_[u].y, f);
            float dv1 = plerp(t4_[u].z, f);
            float dv2 = plerp(t4_[u].w, f);
            axa += plo(vp_[u].x) * dv0 * attn;
            float w1v = phi(vp_[u].x) * dv1;
            float w2v = plo(vp_[u].y) * dv2;
            av0 += plo(vc_[u].x)*w1v + w2v*ex_[u];
            av1 += phi(vc_[u].x)*w1v + w2v*ey_[u];
            av2 += plo(vc_[u].y)*w1v + w2v*ez_[u];
        }
    }
    xa16[(size_t)i*HID + h] = f2b(axa);
    va[(size_t)i*384 + h]       = av0;
    va[(size_t)i*384 + 128 + h] = av1;
    va[(size_t)i*384 + 256 + h] = av2;
}

// ---------------- fused oW GEMM + vecdot + residual update + next-layer LN ----------------
#define OROWS 32
__global__ __launch_bounds__(256) void k_oupd(
    const ushort16* __restrict__ xab16, const ushort16* __restrict__ WT,
    const float* __restrict__ obias,
    float* __restrict__ x, float* __restrict__ vec, ushort16* __restrict__ vecm,
    uint32* __restrict__ vecpack,
    const ushort16* __restrict__ vecout, const float* __restrict__ va,
    const float* __restrict__ lnw_n, const float* __restrict__ lnb_n,
    ushort16* __restrict__ hb16, float* __restrict__ outx, float* __restrict__ outv,
    int N, int fin){
    __shared__ float o_s[OROWS][385];
    int tile = blockIdx.x; int r0 = tile*OROWS;
    int wid = threadIdx.x >> 6, lane = threadIdx.x & 63;
    int l16 = lane & 15, lg = lane >> 4;
    {
        int rr = r0 + (wid & 1)*16;
        const ushort16* ar = xab16 + (size_t)(rr + l16)*HID + lg*8;
        short8 a[4];
        #pragma unroll
        for (int ks = 0; ks < 4; ks++) a[ks] = *(const short8*)(ar + ks*32);
        int cbase = (wid >> 1)*192;
        const ushort16* wt = WT + (size_t)1024*HID;
        #pragma unroll
        for (int ct = 0; ct < 12; ct++){
            f32x4 acc; acc[0]=0.f; acc[1]=0.f; acc[2]=0.f; acc[3]=0.f;
            const ushort16* br = wt + (size_t)(cbase + ct*16 + l16)*HID + lg*8;
            #pragma unroll
            for (int ks = 0; ks < 4; ks++){
                short8 b = *(const short8*)(br + ks*32);
                acc = __builtin_amdgcn_mfma_f32_16x16x32_bf16(a[ks], b, acc, 0, 0, 0);
            }
            int gc = cbase + ct*16 + l16;
            float bb = obias[gc];
            #pragma unroll
            for (int rg = 0; rg < 4; rg++)
                o_s[(wid & 1)*16 + lg*4 + rg][gc] = acc[rg] + bb;
        }
    }
    __syncthreads();
    for (int pass = 0; pass < 8; pass++){
        int nrow = pass*4 + wid;
        int n = r0 + nrow;
        if (n >= N) break;
        const ushort16* vo = vecout + (size_t)n*1152;
        const float* o_r = o_s[nrow];
        size_t vb = (size_t)n*384;
        float xva, xvb, v0a, v0b, v1a, v1b, v2a, v2b;
        #pragma unroll
        for (int half = 0; half < 2; half++){
            int hh = lane + half*64;
            float vdot = b2f(vo[hh])*b2f(vo[128+hh]) + b2f(vo[384+hh])*b2f(vo[512+hh])
                       + b2f(vo[768+hh])*b2f(vo[896+hh]);
            float o1 = o_r[hh], o2 = o_r[128+hh], o3 = o_r[256+hh];
            float xv = x[(size_t)n*HID + hh] + vdot*o2 + o3;
            float v0 = vec[vb + hh]       + b2f(vo[256  + hh])*o1 + va[vb + hh];
            float v1 = vec[vb + 128 + hh] + b2f(vo[640  + hh])*o1 + va[vb + 128 + hh];
            float v2 = vec[vb + 256 + hh] + b2f(vo[1024 + hh])*o1 + va[vb + 256 + hh];
            if (half == 0){ xva = xv; v0a = v0; v1a = v1; v2a = v2; }
            else          { xvb = xv; v0b = v0; v1b = v1; v2b = v2; }
        }
        float s1 = xva + xvb, s2 = xva*xva + xvb*xvb;
        #pragma unroll
        for (int o = 32; o; o >>= 1){ s1 += __shfl_xor(s1, o, 64); s2 += __shfl_xor(s2, o, 64); }
        float mean = s1 * (1.f/HID);
        float var = s2 * (1.f/HID) - mean*mean;
        float inv = rsqrtf(var + 1e-5f);
        #pragma unroll
        for (int half = 0; half < 2; half++){
            int hh = lane + half*64;
            float xv = half ? xvb : xva;
            float v0 = half ? v0b : v0a;
            float v1 = half ? v1b : v1a;
            float v2 = half ? v2b : v2a;
            float lnv = (xv - mean)*inv*lnw_n[hh] + lnb_n[hh];
            if (!fin){
                x[(size_t)n*HID + hh] = xv;
                vec[vb + hh] = v0; vec[vb + 128 + hh] = v1; vec[vb + 256 + hh] = v2;
                vecm[vb + hh] = f2b(v0); vecm[vb + 128 + hh] = f2b(v1); vecm[vb + 256 + hh] = f2b(v2);
                vecpack[(size_t)n*256 + 2*hh]     = packp(v0, v1);
                vecpack[(size_t)n*256 + 2*hh + 1] = packp(v2, 0.f);
                hb16[(size_t)n*HID + hh] = f2b(lnv);
            } else {
                outx[(size_t)n*HID + hh] = lnv;
                outv[vb + hh] = v0; outv[vb + 128 + hh] = v1; outv[vb + 256 + hh] = v2;
            }
        }
    }
}

// ---------------- host ----------------
extern "C" void kernel_launch(void* const* d_in, const int* in_sizes, int n_in,
                              void* d_out, int out_size, void* d_ws, size_t ws_size,
                              hipStream_t stream){
    const int*   z        = (const int*)  d_in[0];
    const int*   ei       = (const int*)  d_in[1];
    const float* edge_vec = (const float*)d_in[2];
    const float* emb      = (const float*)d_in[3];
    const float* means    = (const float*)d_in[4];
    const float* betas    = (const float*)d_in[5];
    const float* ne_emb   = (const float*)d_in[6];
    const float* dpW      = (const float*)d_in[7];
    const float* dpb      = (const float*)d_in[8];
    const float* cbW      = (const float*)d_in[9];
    const float* cbb      = (const float*)d_in[10];
    const float* lnw      = (const float*)d_in[11];
    const float* lnb      = (const float*)d_in[12];
    const float* qW       = (const float*)d_in[13];
    const float* qb       = (const float*)d_in[14];
    const float* kW       = (const float*)d_in[15];
    const float* kb       = (const float*)d_in[16];
    const float* vW       = (const float*)d_in[17];
    const float* vb       = (const float*)d_in[18];
    const float* oW       = (const float*)d_in[19];
    const float* obias    = (const float*)d_in[20];
    const float* vecW     = (const float*)d_in[21];
    const float* dkW      = (const float*)d_in[22];
    const float* dkb      = (const float*)d_in[23];
    const float* dvW      = (const float*)d_in[24];
    const float* dvb      = (const float*)d_in[25];
    const float* onw      = (const float*)d_in[26];
    const float* onb      = (const float*)d_in[27];

    int N = in_sizes[0];
    int E = in_sizes[1] / 2;
    int Nup  = ((N + 63) >> 6) << 6;
    int N3up = ((3*N + 63) >> 6) << 6;

    char* p = (char*)d_ws;
    auto alloc = [&](size_t bytes){ void* r = (void*)p; p += (bytes + 255) & ~(size_t)255; return r; };
    int*      counts  = (int*)     alloc((size_t)N*4);
    int*      offsets = (int*)     alloc((size_t)(N+1)*4);
    int*      cursor  = (int*)     alloc((size_t)N*4);
    int*      eperm   = (int*)     alloc((size_t)E*4);
    int4*     edata   = (int4*)    alloc((size_t)E*16);
    float4*   evn4    = (float4*)  alloc((size_t)E*16);
    uint32*   Tp      = (uint32*)  alloc((size_t)NLAYERS*TSTRIDE*4);
    uint32*   Tne32   = (uint32*)  alloc((size_t)TROWS*HID*4);
    ushort16* WT      = (ushort16*)alloc((size_t)NLAYERS*WCOLS*HID*2);
    float*    kvbias  = (float*)   alloc((size_t)NLAYERS*512*4);
    ushort16* nemb16  = (ushort16*)alloc((size_t)N*HID*2);
    float*    agg     = (float*)   alloc((size_t)N*HID*4);
    float*    xb      = (float*)   alloc((size_t)N*HID*4);
    ushort16* hb16    = (ushort16*)alloc((size_t)Nup*HID*2);
    float*    qb_     = (float*)   alloc((size_t)N*HID*4);
    ushort16* vpack   = (ushort16*)alloc((size_t)N*512*2);
    uint32*   vecpack = (uint32*)  alloc((size_t)N*256*4);
    ushort16* vecm    = (ushort16*)alloc((size_t)N3up*HID*2);
    float*    vecb    = (float*)   alloc((size_t)N*384*4);
    ushort16* vecout  = (ushort16*)alloc((size_t)N*1152*2);
    ushort16* xab16   = (ushort16*)alloc((size_t)Nup*HID*2);
    float*    vab     = (float*)   alloc((size_t)N*384*4);

    hipMemsetAsync(counts, 0, (size_t)N*4, stream);

    int CB  = (E + 255) >> 8;
    int NPB = (N*HID + 255) >> 8;
    k_setup_light<<<CB + NPB + 64 + NLAYERS, 256, 0, stream>>>(
        ei, E, counts, z, ne_emb, nemb16, N,
        hb16, vecm, xab16, Nup, N3up, kb, vb, kvbias);
    k_scan<<<1, 1024, 0, stream>>>(counts, offsets, cursor, N);
    k_scatter<<<(E+255)/256, 256, 0, stream>>>(ei, E, cursor, eperm);
    k_srcsort_vals<<<(N+3)/4, 256, 0, stream>>>(offsets, ei, eperm, edge_vec, N, edata, evn4);

    k_build_tables<<<dim3((TROWS + KB - 1)/KB, NLAYERS), 512, 0, stream>>>(means, betas, dkW, dkb, dvW, dvb, Tp);
    k_build_ne<<<TROWS, 128, 0, stream>>>(means, betas, dpW, dpb, Tne32);
    k_build_wt<<<dim3(WCOLS/32, NLAYERS), 256, 0, stream>>>(qW, kW, vW, vecW, oW, WT);
    k_ne_agg<<<N, 128, 0, stream>>>(offsets, edata, Tne32, nemb16, agg);
    k_combine_ln<<<(N+7)/8, 128, 0, stream>>>(z, emb, agg, cbW, cbb, lnw, lnb,
                                              xb, hb16, vecb, vecm, vecpack, N);

    float* outx = (float*)d_out;
    float* outv = (float*)d_out + (size_t)N*HID;

    int NT1 = (N + 63) >> 6;
    int NT3 = (3*N + 63) >> 6;
    for (int l = 0; l < NLAYERS; l++){
        const ushort16* WTl = WT + (size_t)l*WCOLS*HID;
        k_mfma01<<<10*NT1 + 6*NT3, 256, 0, stream>>>(hb16, vecm, WTl,
            qb + (size_t)l*HID, kvbias + (size_t)l*512,
            qb_, vpack, vecout, N);
        k_edge_agg<<<N, 128, 0, stream>>>(offsets, edata, evn4, Tp + (size_t)l*TSTRIDE,
                                          qb_, vpack, vecpack, xab16, vab);
        int fin = (l == NLAYERS-1);
        k_oupd<<<(N + OROWS - 1)/OROWS, 256, 0, stream>>>(xab16, WTl, obias + (size_t)l*384,
            xb, vecb, vecm, vecpack, vecout, vab,
            fin ? onw : lnw + (size_t)(l+1)*HID,
            fin ? onb : lnb + (size_t)(l+1)*HID,
            hb16, outx, outv, N, fin);
    }
}